// Round 4
// baseline (357.878 us; speedup 1.0000x reference)
//
#include <hip/hip_runtime.h>
#include <hip/hip_fp16.h>
#include <hip/hip_fp8.h>

#define NNODES 4096
#define LWALK 16
#define ODIM 8

#define FP8_SCALE 256.0f
#define FP8_INV   0.00390625f          // 1/256
#define FP8_INV2  1.52587890625e-05f   // 1/65536

typedef unsigned int uint4n __attribute__((ext_vector_type(4)));
typedef float float2n __attribute__((ext_vector_type(2)));

// ---------- fp8 helpers ----------
__device__ __forceinline__ void dec8f(unsigned int lo, unsigned int hi, float* f) {
#if __has_builtin(__builtin_amdgcn_cvt_pk_f32_fp8)
    float2n p;
    p = __builtin_amdgcn_cvt_pk_f32_fp8((int)lo, false); f[0] = p.x; f[1] = p.y;
    p = __builtin_amdgcn_cvt_pk_f32_fp8((int)lo, true);  f[2] = p.x; f[3] = p.y;
    p = __builtin_amdgcn_cvt_pk_f32_fp8((int)hi, false); f[4] = p.x; f[5] = p.y;
    p = __builtin_amdgcn_cvt_pk_f32_fp8((int)hi, true);  f[6] = p.x; f[7] = p.y;
#else
    unsigned int w[2] = {lo, hi};
    const unsigned char* b = (const unsigned char*)w;
#pragma unroll
    for (int i = 0; i < 8; ++i) {
        __hip_fp8_e4m3 t; t.__x = b[i]; f[i] = (float)t;
    }
#endif
}

__device__ __forceinline__ void enc8f(const float* a, unsigned int* lo,
                                      unsigned int* hi) {
#if __has_builtin(__builtin_amdgcn_cvt_pk_fp8_f32)
    int l = 0, h = 0;
    l = __builtin_amdgcn_cvt_pk_fp8_f32(a[0], a[1], l, false);
    l = __builtin_amdgcn_cvt_pk_fp8_f32(a[2], a[3], l, true);
    h = __builtin_amdgcn_cvt_pk_fp8_f32(a[4], a[5], h, false);
    h = __builtin_amdgcn_cvt_pk_fp8_f32(a[6], a[7], h, true);
    *lo = (unsigned int)l; *hi = (unsigned int)h;
#else
    unsigned char b[8];
#pragma unroll
    for (int i = 0; i < 8; ++i)
        b[i] = __hip_cvt_float_to_fp8(a[i], __HIP_SATFINITE, __HIP_E4M3);
    unsigned int w[2];
    __builtin_memcpy(w, b, 8);
    *lo = w[0]; *hi = w[1];
#endif
}

__device__ __forceinline__ void dec16f(uint4n w, float* f) {
    dec8f(w.x, w.y, f);
    dec8f(w.z, w.w, f + 8);
}

__device__ __forceinline__ uint4n enc16f(const float* a) {
    uint4n o;
    unsigned int lo, hi;
    enc8f(a, &lo, &hi);     o.x = lo; o.y = hi;
    enc8f(a + 8, &lo, &hi); o.z = lo; o.w = hi;
    return o;
}

__device__ __forceinline__ unsigned char enc1f(float f) {
#if __has_builtin(__builtin_amdgcn_cvt_pk_fp8_f32)
    return (unsigned char)(__builtin_amdgcn_cvt_pk_fp8_f32(f, 0.f, 0, false) & 0xFF);
#else
    return __hip_cvt_float_to_fp8(f, __HIP_SATFINITE, __HIP_E4M3);
#endif
}

__device__ __forceinline__ float decw(unsigned int packed) {
    return __half2float(__ushort_as_half((unsigned short)(packed >> 16)));
}

// ---------- edge-index dtype detection ----------
__global__ void detect_fmt_k(const void* ei, int E, int* flag) {
    if (blockIdx.x == 0 && threadIdx.x == 0) {
        const long long* p = (const long long*)ei;
        int ok = 1;
        for (int i = 0; i < 64; ++i) {
            long long v = p[i];
            if (v < 0 || v >= NNODES) { ok = 0; break; }
        }
        *flag = ok;
    }
}

__device__ __forceinline__ int load_idx(const void* p, int i, int fmt) {
    if (fmt) return (int)((const long long*)p)[i];
    return ((const int*)p)[i];
}

__global__ void build_deg_cnt_k(const void* ei, int E, int* deg, int* cnt,
                                const int* fmt) {
    int e = blockIdx.x * blockDim.x + threadIdx.x;
    if (e >= E) return;
    int f = *fmt;
    int r = load_idx(ei, e, f);
    int c = load_idx(ei, E + e, f);
    atomicAdd(&deg[r], 1);    // out-degree
    atomicAdd(&cnt[c], 1);    // in-degree
}

// ---------- exclusive scan over padded (multiple-of-4) counts ----------
__global__ void scan_k(const int* __restrict__ cnt, int* __restrict__ rowptr,
                       int* __restrict__ cursor) {
    __shared__ int sm[1024];
    int tid = threadIdx.x;
    int v0 = (cnt[4 * tid + 0] + 3) & ~3;
    int v1 = (cnt[4 * tid + 1] + 3) & ~3;
    int v2 = (cnt[4 * tid + 2] + 3) & ~3;
    int v3 = (cnt[4 * tid + 3] + 3) & ~3;
    int tsum = v0 + v1 + v2 + v3;
    sm[tid] = tsum;
    __syncthreads();
    int val = tsum;
    for (int off = 1; off < 1024; off <<= 1) {
        int t = (tid >= off) ? sm[tid - off] : 0;
        __syncthreads();
        val += t;
        sm[tid] = val;
        __syncthreads();
    }
    int excl = val - tsum;
    int p0 = excl, p1 = excl + v0, p2 = p1 + v1, p3 = p2 + v2;
    rowptr[4 * tid + 0] = p0; rowptr[4 * tid + 1] = p1;
    rowptr[4 * tid + 2] = p2; rowptr[4 * tid + 3] = p3;
    cursor[4 * tid + 0] = p0; cursor[4 * tid + 1] = p1;
    cursor[4 * tid + 2] = p2; cursor[4 * tid + 3] = p3;
    if (tid == 1023) rowptr[4096] = val;
}

// ---------- fill CSRs ----------
// in-CSR (by destination): packed 4B edge = fp16(1/deg(src))<<16 | src
// out-CSR (by source): 4B dest index; true end tracked by ocursor (no pads).
__global__ void fill_pad_k(const void* ei, int E, const int* __restrict__ deg,
                           int* cursor, int* ocursor,
                           unsigned int* __restrict__ ep4,
                           unsigned int* __restrict__ oidx, const int* fmt) {
    int e = blockIdx.x * blockDim.x + threadIdx.x;
    if (e < E) {
        int f = *fmt;
        int r = load_idx(ei, e, f);
        int c = load_idx(ei, E + e, f);
        int d = deg[r];
        float v = 1.0f / (float)(d < 1 ? 1 : d);
        int pos = atomicAdd(&cursor[c], 1);
        unsigned hv = (unsigned)__half_as_ushort(__float2half(v));
        ep4[pos] = (hv << 16) | (unsigned)r;
        int opos = atomicAdd(&ocursor[r], 1);
        oidx[opos] = (unsigned)c;
    }
}

__global__ void pad_fill_k(const int* __restrict__ rowptr,
                           const int* __restrict__ cursor,
                           unsigned int* __restrict__ ep4) {
    int c = blockIdx.x * blockDim.x + threadIdx.x;
    if (c >= NNODES) return;
    for (int p = cursor[c]; p < rowptr[c + 1]; ++p)
        ep4[p] = 0u;   // src=0, v(fp16)=0 -> contributes nothing
}

// ---------- fused chain: X2 build (out-walk) + X3..X8 SpMM per 16-col slab ---
// Block owns columns [S0,S0+16). buf[r][cl] = X_k[r, S0+cl] (fp8, x256).
// Phase 1 builds COLUMNS of X2 via the OUT-edge two-level walk:
//   X2[s,gc] = sum_{gc->m->s} (1/deg gc)(1/deg m)      [round-3 bug fix]
// Diags k1..k8 extracted in-slab from fp32 accumulators; X4,X5,X7,X8 -> HBM.
__global__ __launch_bounds__(512, 1) void chain_k(
    const int* __restrict__ rowptr, const unsigned int* __restrict__ ep4,
    const int* __restrict__ orowptr, const int* __restrict__ ocursor,
    const unsigned int* __restrict__ oidx, const int* __restrict__ deg,
    float* __restrict__ rw,
    unsigned char* __restrict__ M4, unsigned char* __restrict__ M5,
    unsigned char* __restrict__ M7, unsigned char* __restrict__ M8) {
    __shared__ unsigned char bufA[NNODES * 16];
    __shared__ unsigned char bufB[NNODES * 16];
    const int t = threadIdx.x;
    const int bid = blockIdx.x;
    const int slab = (bid & 7) * 32 + (bid >> 3);   // sibling slabs per XCD
    const int S0 = slab * 16;

    // ---- Phase 1: X2 columns S0..S0+15 ----
    float* col32 = (float*)bufB;          // 16 KB fp32 scratch (bufB dead)
    const int g = t >> 4;                 // edge1 slot [0,32)
    const int l = t & 15;                 // edge2 lane [0,16)
    for (int cl = 0; cl < 16; ++cl) {
        const int gc = S0 + cl;
        for (int i = t; i < NNODES; i += 512) col32[i] = 0.f;
        __syncthreads();
        const int dg = deg[gc];
        const float vg = 1.f / (float)(dg < 1 ? 1 : dg);
        const int ob = orowptr[gc], oe = ocursor[gc];
        for (int p1 = ob + g; p1 < oe; p1 += 32) {
            int m = (int)oidx[p1];
            if (m == gc && l == 0)
                atomicAdd(&rw[gc * LWALK + 0], vg);   // k=1 diag (self-loops)
            int dm = deg[m];
            float vm = vg / (float)(dm < 1 ? 1 : dm);
            int mb = orowptr[m], me = ocursor[m];
            for (int p2 = mb + l; p2 < me; p2 += 16)
                atomicAdd(&col32[oidx[p2]], vm);
        }
        __syncthreads();
        if (t == 0) rw[gc * LWALK + 1] = col32[gc];   // k=2 diag (fp32)
        for (int i = t; i < NNODES; i += 512)
            bufA[i * 16 + cl] = enc1f(col32[i] * FP8_SCALE);
        __syncthreads();
    }

    // ---- Phase 2: X3..X8 LDS->LDS SpMM; diags k3..k8; store X4,X5,X7,X8 ----
    int rpb[8], rpe[8];
#pragma unroll
    for (int j = 0; j < 8; ++j) {
        rpb[j] = rowptr[t + 512 * j];
        rpe[j] = rowptr[t + 512 * j + 1];
    }
#pragma unroll 1
    for (int k = 3; k <= 8; ++k) {
        const unsigned char* src = (k & 1) ? bufA : bufB;
        unsigned char* dst = (k & 1) ? bufB : bufA;
        __syncthreads();
#pragma unroll 1
        for (int j = 0; j < 8; ++j) {
            const int c = t + 512 * j;
            float acc[16];
#pragma unroll
            for (int u = 0; u < 16; ++u) acc[u] = 0.f;
            for (int e = rpb[j]; e < rpe[j]; e += 4) {
                uint4n ew = *(const uint4n*)(ep4 + e);
                uint4n x0 = *(const uint4n*)(src + (ew.x & 0xFFFFu) * 16);
                uint4n x1 = *(const uint4n*)(src + (ew.y & 0xFFFFu) * 16);
                uint4n x2 = *(const uint4n*)(src + (ew.z & 0xFFFFu) * 16);
                uint4n x3 = *(const uint4n*)(src + (ew.w & 0xFFFFu) * 16);
                float f[16];
                float v;
                v = decw(ew.x);
                dec16f(x0, f);
#pragma unroll
                for (int u = 0; u < 16; ++u) acc[u] = fmaf(f[u], v, acc[u]);
                v = decw(ew.y);
                dec16f(x1, f);
#pragma unroll
                for (int u = 0; u < 16; ++u) acc[u] = fmaf(f[u], v, acc[u]);
                v = decw(ew.z);
                dec16f(x2, f);
#pragma unroll
                for (int u = 0; u < 16; ++u) acc[u] = fmaf(f[u], v, acc[u]);
                v = decw(ew.w);
                dec16f(x3, f);
#pragma unroll
                for (int u = 0; u < 16; ++u) acc[u] = fmaf(f[u], v, acc[u]);
            }
            if ((unsigned)(c - S0) < 16u) {
                float d = 0.f;
#pragma unroll
                for (int u = 0; u < 16; ++u)
                    if (c - S0 == u) d = acc[u];
                rw[c * LWALK + (k - 1)] = d * FP8_INV;   // diag k (fp32 pre-quant)
            }
            uint4n o = enc16f(acc);
            *(uint4n*)(dst + c * 16) = o;
        }
        __syncthreads();
        if (k == 4 || k == 5 || k == 7 || k == 8) {
            unsigned char* M = (k == 4) ? M4 : (k == 5) ? M5 : (k == 7) ? M7 : M8;
#pragma unroll 1
            for (int j = 0; j < 8; ++j) {
                const int c = t + 512 * j;
                uint4n o = *(const uint4n*)(dst + c * 16);
                *(uint4n*)(M + (size_t)c * NNODES + S0) = o;
            }
        }
    }
}

// ---------- pairdiags k9..k16: 4 groups x 1024 blocks, one launch ----------
// grp g computes colO = diag(PA*PB1), colE = diag(PA*PB2):
//   g0: (X5,X4,X5)->k9,k10   g1: (X7,X4,X7)->k11,k14
//   g2: (X8,X4,X8)->k12,k16  g3: (X8,X5,X7)->k13,k15
__global__ __launch_bounds__(256) void pairall_k(
    const unsigned char* __restrict__ M4, const unsigned char* __restrict__ M5,
    const unsigned char* __restrict__ M7, const unsigned char* __restrict__ M8,
    float* __restrict__ rw) {
    __shared__ __half bt[64][66];
    __shared__ __half ct[64][66];
    const int bid = blockIdx.x;
    const int grp = bid >> 10;
    const int pb = bid & 1023;
    const unsigned char* PA;
    const unsigned char* PB1;
    const unsigned char* PB2;
    int colO, colE;
    if (grp == 0)      { PA = M5; PB1 = M4; PB2 = M5; colO = 8;  colE = 9;  }
    else if (grp == 1) { PA = M7; PB1 = M4; PB2 = M7; colO = 10; colE = 13; }
    else if (grp == 2) { PA = M8; PB1 = M4; PB2 = M8; colO = 11; colE = 15; }
    else               { PA = M8; PB1 = M5; PB2 = M7; colO = 12; colE = 14; }
    const int i0 = (pb & 63) * 64;
    const int Jbeg = (pb >> 6) * (NNODES / 16);
    const int Jend = Jbeg + (NNODES / 16);
    const int t = threadIdx.x;
    const int li = t >> 2;
    const int q = t & 3;
    const int c0 = q * 16;
    float accO = 0.f, accE = 0.f;
    for (int J = Jbeg; J < Jend; J += 64) {
        uint4n b16 = __builtin_nontemporal_load(
            (const uint4n*)(PB1 + (size_t)(J + li) * NNODES + i0 + c0));
        uint4n g16 = __builtin_nontemporal_load(
            (const uint4n*)(PB2 + (size_t)(J + li) * NNODES + i0 + c0));
        __syncthreads();
        float bf[16], gf[16];
        dec16f(b16, bf);
        dec16f(g16, gf);
#pragma unroll
        for (int s = 0; s < 16; ++s) {
            bt[c0 + s][li] = __float2half(bf[s]);  // fp8 values exact in fp16
            ct[c0 + s][li] = __float2half(gf[s]);
        }
        __syncthreads();
        uint4n a16 = __builtin_nontemporal_load(
            (const uint4n*)(PA + (size_t)(i0 + li) * NNODES + J + c0));
        float af[16];
        dec16f(a16, af);
#pragma unroll
        for (int s = 0; s < 16; ++s) {
            accO = fmaf(af[s], __half2float(bt[li][c0 + s]), accO);
            accE = fmaf(af[s], __half2float(ct[li][c0 + s]), accE);
        }
    }
    accO += __shfl_xor(accO, 1);
    accO += __shfl_xor(accO, 2);
    accE += __shfl_xor(accE, 1);
    accE += __shfl_xor(accE, 2);
    if (q == 0) {
        atomicAdd(&rw[(i0 + li) * LWALK + colO], accO * FP8_INV2);
        atomicAdd(&rw[(i0 + li) * LWALK + colE], accE * FP8_INV2);
    }
}

// ---------- final linear ----------
__global__ void linear_k(const float* __restrict__ rw, const float* __restrict__ W,
                         const float* __restrict__ b, float* __restrict__ out) {
    int i = blockIdx.x * blockDim.x + threadIdx.x;
    if (i >= NNODES * ODIM) return;
    int s = i >> 3, d = i & 7;
    float acc = b[d];
#pragma unroll
    for (int k = 0; k < LWALK; ++k)
        acc = fmaf(rw[s * LWALK + k], W[d * LWALK + k], acc);
    out[i] = acc;
}

extern "C" void kernel_launch(void* const* d_in, const int* in_sizes, int n_in,
                              void* d_out, int out_size, void* d_ws, size_t ws_size,
                              hipStream_t stream) {
    const void* ei = d_in[0];
    int E = in_sizes[0] / 2;
    const float* W = (const float*)d_in[2];
    const float* bias = (const float*)d_in[3];
    float* out = (float*)d_out;

    char* ws = (char*)d_ws;
    size_t off = 0;
    auto alloc = [&](size_t bytes) -> char* {
        char* p = ws + off;
        off = (off + bytes + 255) & ~(size_t)255;
        return p;
    };
    int* flag = (int*)alloc(4);
    int* deg = (int*)alloc(NNODES * 4);
    int* cnt = (int*)alloc(NNODES * 4);
    int* rowptr = (int*)alloc((NNODES + 1) * 4);
    int* cursor = (int*)alloc(NNODES * 4);
    int* orowptr = (int*)alloc((NNODES + 1) * 4);
    int* ocursor = (int*)alloc(NNODES * 4);
    unsigned int* ep4 = (unsigned int*)alloc(((size_t)E + 4 * NNODES) * 4);
    unsigned int* oidx = (unsigned int*)alloc(((size_t)E + 4 * NNODES) * 4);
    float* rw = (float*)alloc(NNODES * LWALK * 4);
    unsigned char* M4 = (unsigned char*)alloc((size_t)NNODES * NNODES);
    unsigned char* M5 = (unsigned char*)alloc((size_t)NNODES * NNODES);
    unsigned char* M7 = (unsigned char*)alloc((size_t)NNODES * NNODES);
    unsigned char* M8 = (unsigned char*)alloc((size_t)NNODES * NNODES);

    (void)hipMemsetAsync(deg, 0, NNODES * 4, stream);
    (void)hipMemsetAsync(cnt, 0, NNODES * 4, stream);
    (void)hipMemsetAsync(rw, 0, NNODES * LWALK * 4, stream);
    detect_fmt_k<<<1, 64, 0, stream>>>(ei, E, flag);
    build_deg_cnt_k<<<(E + 255) / 256, 256, 0, stream>>>(ei, E, deg, cnt, flag);
    scan_k<<<1, 1024, 0, stream>>>(cnt, rowptr, cursor);     // in-CSR
    scan_k<<<1, 1024, 0, stream>>>(deg, orowptr, ocursor);   // out-CSR
    fill_pad_k<<<(E + 255) / 256, 256, 0, stream>>>(ei, E, deg, cursor, ocursor,
                                                    ep4, oidx, flag);
    pad_fill_k<<<(NNODES + 255) / 256, 256, 0, stream>>>(rowptr, cursor, ep4);

    // Fused chain: X2 (out-walk) + X3..X8 in LDS; diags k1..k8;
    // X4,X5,X7,X8 -> HBM for the pair stage.
    chain_k<<<256, 512, 0, stream>>>(rowptr, ep4, orowptr, ocursor, oidx, deg,
                                     rw, M4, M5, M7, M8);

    // Pairdiags k9..k16.
    pairall_k<<<4096, 256, 0, stream>>>(M4, M5, M7, M8, rw);

    linear_k<<<(NNODES * ODIM + 255) / 256, 256, 0, stream>>>(rw, W, bias, out);
}